// Round 8
// baseline (975.586 us; speedup 1.0000x reference)
//
#include <hip/hip_runtime.h>
#include <hip/hip_bf16.h>
#include <stdint.h>

typedef __attribute__((ext_vector_type(8))) short short8;
typedef __attribute__((ext_vector_type(8))) unsigned short ushort8;
typedef __attribute__((ext_vector_type(4))) float f32x4;

#define K_DIM 4096
#define N_DIM 11008
#define M_DIM 8192
#define BM 256
#define BN 256
#define BK 64
#define TILES (K_DIM / BK)   // 64

__constant__ float c_nf4[16] = {
    -1.0f, -0.6961928009986877f, -0.5250730514526367f, -0.39491748809814453f,
    -0.28444138169288635f, -0.18477343022823334f, -0.09105003625154495f, 0.0f,
    0.07958029955625534f, 0.16093020141124725f, 0.24611230194568634f,
    0.33791524171829224f, 0.44070982933044434f, 0.5626170039176941f,
    0.7229568362236023f, 1.0f};

__device__ __forceinline__ unsigned short f2bf(float f) {
    uint32_t u = __float_as_uint(f);
    u += 0x7fffu + ((u >> 16) & 1u);   // round-to-nearest-even (finite inputs)
    return (unsigned short)(u >> 16);
}

__global__ __launch_bounds__(256) void nf4_dequant_w(const int* __restrict__ q,
                                                     const float* __restrict__ absmax,
                                                     unsigned short* __restrict__ w) {
    __shared__ float lut[16];
    if (threadIdx.x < 16) lut[threadIdx.x] = c_nf4[threadIdx.x];
    __syncthreads();
    size_t t = (size_t)blockIdx.x * 256 + threadIdx.x;
    const int4* q4 = (const int4*)q;
    int4 qa = q4[2 * t];
    int4 qb = q4[2 * t + 1];
    float s = absmax[t >> 3];
    ushort8 o;
    o[0] = f2bf(lut[qa.x & 15] * s);
    o[1] = f2bf(lut[qa.y & 15] * s);
    o[2] = f2bf(lut[qa.z & 15] * s);
    o[3] = f2bf(lut[qa.w & 15] * s);
    o[4] = f2bf(lut[qb.x & 15] * s);
    o[5] = f2bf(lut[qb.y & 15] * s);
    o[6] = f2bf(lut[qb.z & 15] * s);
    o[7] = f2bf(lut[qb.w & 15] * s);
    ((ushort8*)w)[t] = o;
}

__global__ __launch_bounds__(256) void x_to_bf16(const float* __restrict__ x,
                                                 unsigned short* __restrict__ xb) {
    size_t t = (size_t)blockIdx.x * 256 + threadIdx.x;
    const float4* x4 = (const float4*)x;
    float4 a = x4[2 * t];
    float4 b = x4[2 * t + 1];
    ushort8 o;
    o[0] = f2bf(a.x); o[1] = f2bf(a.y); o[2] = f2bf(a.z); o[3] = f2bf(a.w);
    o[4] = f2bf(b.x); o[5] = f2bf(b.y); o[6] = f2bf(b.z); o[7] = f2bf(b.w);
    ((ushort8*)xb)[t] = o;
}

// Stage one 128-row half [128][64] (16 KB): 2 gloads/thread, LDS dest linear,
// GLOBAL source chunk G4-swizzled (r4/r6/r7-proven zero-conflict):
// LDS slot (r, s) holds global chunk s ^ (r&7).
#define STAGE_HALF(gbase, lds_half, row0, k0)                                 \
  do {                                                                        \
    _Pragma("unroll")                                                         \
    for (int _g = 0; _g < 2; ++_g) {                                          \
      const int _i = _g * 512 + tid;       /* slot 0..1023 */                 \
      const int _r = _i >> 3;              /* local row 0..127 */             \
      const int _c = (_i & 7) ^ (_r & 7);  /* global chunk */                 \
      __builtin_amdgcn_global_load_lds(                                       \
          (const __attribute__((address_space(1))) void*)((gbase) +           \
              (size_t)((row0) + _r) * K_DIM + (k0) + _c * 8),                 \
          (__attribute__((address_space(3))) void*)((lds_half) +              \
              (_g * 512 + wave * 64) * 8),                                    \
          16, 0, 0);                                                          \
    }                                                                         \
  } while (0)

// Frag reads from a [128][64] half into a NAMED register set (rule 20).
#define DS_A4(dst, rbase, X)                                                  \
  dst[0] = *(const short8*)(Ah + ((rbase) +  0) * 64 + (roff ^ (X)));         \
  dst[1] = *(const short8*)(Ah + ((rbase) + 16) * 64 + (roff ^ (X)));         \
  dst[2] = *(const short8*)(Ah + ((rbase) + 32) * 64 + (roff ^ (X)));         \
  dst[3] = *(const short8*)(Ah + ((rbase) + 48) * 64 + (roff ^ (X)));

#define DS_B4(dst, X)                                                         \
  dst[0] = *(const short8*)(Bh + (bbase +  0) * 64 + (roff ^ (X)));           \
  dst[1] = *(const short8*)(Bh + (bbase + 16) * 64 + (roff ^ (X)));           \
  dst[2] = *(const short8*)(Bh + (bbase + 32) * 64 + (roff ^ (X)));           \
  dst[3] = *(const short8*)(Bh + (bbase + 48) * 64 + (roff ^ (X)));

#define MFMA16(MI0, Ar, Br)                                                   \
  do {                                                                        \
    _Pragma("unroll")                                                         \
    for (int _m = 0; _m < 4; ++_m) {                                          \
      _Pragma("unroll")                                                       \
      for (int _n = 0; _n < 4; ++_n)                                          \
        acc[(MI0) + _m][_n] = __builtin_amdgcn_mfma_f32_16x16x32_bf16(        \
            Ar[_m], Br[_n], acc[(MI0) + _m][_n], 0, 0, 0);                    \
    }                                                                         \
  } while (0)

#define BAR   asm volatile("s_barrier" ::: "memory")
#define LGKM0 do { asm volatile("s_waitcnt lgkmcnt(0)" ::: "memory");         \
                   __builtin_amdgcn_sched_barrier(0); } while (0)

// Lockstep phase: all waves arrive at BAR fast (reads are issue-and-go);
// per-wave lgkm(0) clears in LDS-queue order -> staggered MFMA starts
// pipeline DS under MFMA (the m201 mechanism). setprio keeps MFMA waves fed.
#define PHASE_MFMA(MI0, Ar, Br)                                               \
  BAR; LGKM0;                                                                 \
  __builtin_amdgcn_s_setprio(1);                                              \
  MFMA16(MI0, Ar, Br);                                                        \
  __builtin_amdgcn_s_setprio(0);                                              \
  __builtin_amdgcn_sched_barrier(0)

// 256x256 tile, BK=64, 8 waves (2M x 4N), dbuf-2, G4 zero-conflict swizzle,
// faithful m201 4-phase lockstep (2 barriers/phase), 16 MFMA per phase.
__global__ __launch_bounds__(512, 2) void gemm256(const unsigned short* __restrict__ A,
                                                  const unsigned short* __restrict__ B,
                                                  const float* __restrict__ bias,
                                                  float* __restrict__ C) {
    __shared__ unsigned short As[2][2][128 * 64];   // [buf][row-half], 64 KB
    __shared__ unsigned short Bs[2][2][128 * 64];   // 64 KB -> 128 KB total

    const int tid  = threadIdx.x;
    const int wave = tid >> 6;
    const int lane = tid & 63;
    const int wm = wave >> 2;               // 0..1 -> A row-half
    const int wn = wave & 3;                // 0..3 -> 64-row B slab
    const int lr = lane & 15;
    const int q  = lane >> 4;               // 0..3
    // Zero-conflict swizzled read offset (elements), kk=0; kk=32 -> roff^32.
    const int roff = lr * 64 + ((q ^ (lr & 7)) << 3);
    const int bbase = (wn & 1) * 64;        // B row base within its half

    // XCD-aware bijective swizzle: grid = 1376, 1376 % 8 == 0.
    const int nbn = N_DIM / BN;             // 43
    const int cpx = (int)gridDim.x >> 3;    // 172
    const int bid = (int)blockIdx.x;
    const int swz = (bid & 7) * cpx + (bid >> 3);
    const int bm = swz / nbn;
    const int bn = swz % nbn;

    const unsigned short* Ab = A + (size_t)bm * BM * K_DIM;
    const unsigned short* Bb = B + (size_t)bn * BN * K_DIM;

    f32x4 acc[8][4];
#pragma unroll
    for (int i = 0; i < 8; ++i)
#pragma unroll
        for (int j = 0; j < 4; ++j)
#pragma unroll
            for (int v = 0; v < 4; ++v) acc[i][j][v] = 0.0f;

    // Prologue: stage tile 0 (4 halves, 8 loads/thread); drain; barrier.
    STAGE_HALF(Ab, &As[0][0][0], 0,   0); STAGE_HALF(Bb, &Bs[0][0][0], 0,   0);
    STAGE_HALF(Ab, &As[0][1][0], 128, 0); STAGE_HALF(Bb, &Bs[0][1][0], 128, 0);
    asm volatile("s_waitcnt vmcnt(0)" ::: "memory");
    BAR;

    short8 aA[4], aB[4], aC[4], aD[4], bE[4], bO[4];

#pragma unroll 1
    for (int t = 0; t < TILES; ++t) {
        const int p = t & 1;
        int t1 = t + 1; if (t1 >= TILES) t1 = 0;   // tail wrap: harmless
        const int k1 = t1 * BK;
        const unsigned short* Ah = &As[p][wm][0];
        const unsigned short* Bh = &Bs[p][wn >> 1][0];

        // ---- P1: mi 0..3 kk=0; reads aA+bE; stage t+1 A-h0 + B-h0 ----
        DS_A4(aA, 0, 0);
        DS_B4(bE, 0);
        STAGE_HALF(Ab, &As[p ^ 1][0][0], 0, k1);
        STAGE_HALF(Bb, &Bs[p ^ 1][0][0], 0, k1);
        PHASE_MFMA(0, aA, bE);
        BAR;

        // ---- P2: mi 4..7 kk=0; reads aB (bE live); stage t+1 A-h1 ----
        DS_A4(aB, 64, 0);
        STAGE_HALF(Ab, &As[p ^ 1][1][0], 128, k1);
        PHASE_MFMA(4, aB, bE);
        BAR;

        // ---- P3: mi 0..3 kk=32; reads aC+bO; stage t+1 B-h1 ----
        DS_A4(aC, 0, 32);
        DS_B4(bO, 32);
        STAGE_HALF(Bb, &Bs[p ^ 1][1][0], 128, k1);
        PHASE_MFMA(0, aC, bO);
        BAR;

        // ---- P4: mi 4..7 kk=32; reads aD (bO live); no stage ----
        DS_A4(aD, 64, 32);
        PHASE_MFMA(4, aD, bO);
        // Drain t+1's 8 loads (last issued ~1.5 phases ago -> ~free), then
        // release: next tile reads buf p^1.
        asm volatile("s_waitcnt vmcnt(0)" ::: "memory");
        BAR;
    }
    asm volatile("s_waitcnt vmcnt(0)" ::: "memory");

    // Epilogue: C/D layout col = lane&15, row = (lane>>4)*4 + v (m89/m91).
    const int row0 = bm * BM + wm * 128 + (q << 2);
    const int col0 = bn * BN + wn * 64 + lr;
#pragma unroll
    for (int ni = 0; ni < 4; ++ni) {
        const int col = col0 + ni * 16;
        const float bv = bias[col];
#pragma unroll
        for (int mi = 0; mi < 8; ++mi) {
#pragma unroll
            for (int v = 0; v < 4; ++v) {
                C[(size_t)(row0 + mi * 16 + v) * N_DIM + col] = acc[mi][ni][v] + bv;
            }
        }
    }
}

extern "C" void kernel_launch(void* const* d_in, const int* in_sizes, int n_in,
                              void* d_out, int out_size, void* d_ws, size_t ws_size,
                              hipStream_t stream) {
    const float* x    = (const float*)d_in[0];   // [4,2048,4096] f32
    const int*   wq   = (const int*)d_in[1];     // [11008,4096] int32 in 0..15
    const float* am   = (const float*)d_in[2];   // [11008,64] f32
    const float* bias = (const float*)d_in[3];   // [11008] f32
    float* out = (float*)d_out;                  // [4,2048,11008] f32

    const size_t w_elems = (size_t)N_DIM * K_DIM;
    const size_t x_elems = (size_t)M_DIM * K_DIM;
    const size_t need = (w_elems + x_elems) * sizeof(unsigned short);
    if (ws_size < need) return;

    unsigned short* wbf = (unsigned short*)d_ws;
    unsigned short* xbf = wbf + w_elems;

    nf4_dequant_w<<<(int)(w_elems / 8 / 256), 256, 0, stream>>>(wq, am, wbf);
    x_to_bf16<<<(int)(x_elems / 8 / 256), 256, 0, stream>>>(x, xbf);

    const int grid = (M_DIM / BM) * (N_DIM / BN);   // 32 * 43 = 1376
    gemm256<<<grid, 512, 0, stream>>>(xbf, wbf, bias, out);
}

// Round 9
// 915.730 us; speedup vs baseline: 1.0654x; 1.0654x over previous
//
#include <hip/hip_runtime.h>
#include <hip/hip_bf16.h>
#include <stdint.h>

typedef __attribute__((ext_vector_type(8))) short short8;
typedef __attribute__((ext_vector_type(8))) unsigned short ushort8;
typedef __attribute__((ext_vector_type(4))) float f32x4;

#define K_DIM 4096
#define N_DIM 11008
#define M_DIM 8192
#define BM 256
#define BN 256
#define BK 64
#define TILES (K_DIM / BK)   // 64

__constant__ float c_nf4[16] = {
    -1.0f, -0.6961928009986877f, -0.5250730514526367f, -0.39491748809814453f,
    -0.28444138169288635f, -0.18477343022823334f, -0.09105003625154495f, 0.0f,
    0.07958029955625534f, 0.16093020141124725f, 0.24611230194568634f,
    0.33791524171829224f, 0.44070982933044434f, 0.5626170039176941f,
    0.7229568362236023f, 1.0f};

__device__ __forceinline__ unsigned short f2bf(float f) {
    uint32_t u = __float_as_uint(f);
    u += 0x7fffu + ((u >> 16) & 1u);   // round-to-nearest-even (finite inputs)
    return (unsigned short)(u >> 16);
}

__global__ __launch_bounds__(256) void nf4_dequant_w(const int* __restrict__ q,
                                                     const float* __restrict__ absmax,
                                                     unsigned short* __restrict__ w) {
    __shared__ float lut[16];
    if (threadIdx.x < 16) lut[threadIdx.x] = c_nf4[threadIdx.x];
    __syncthreads();
    size_t t = (size_t)blockIdx.x * 256 + threadIdx.x;
    const int4* q4 = (const int4*)q;
    int4 qa = q4[2 * t];
    int4 qb = q4[2 * t + 1];
    float s = absmax[t >> 3];
    ushort8 o;
    o[0] = f2bf(lut[qa.x & 15] * s);
    o[1] = f2bf(lut[qa.y & 15] * s);
    o[2] = f2bf(lut[qa.z & 15] * s);
    o[3] = f2bf(lut[qa.w & 15] * s);
    o[4] = f2bf(lut[qb.x & 15] * s);
    o[5] = f2bf(lut[qb.y & 15] * s);
    o[6] = f2bf(lut[qb.z & 15] * s);
    o[7] = f2bf(lut[qb.w & 15] * s);
    ((ushort8*)w)[t] = o;
}

__global__ __launch_bounds__(256) void x_to_bf16(const float* __restrict__ x,
                                                 unsigned short* __restrict__ xb) {
    size_t t = (size_t)blockIdx.x * 256 + threadIdx.x;
    const float4* x4 = (const float4*)x;
    float4 a = x4[2 * t];
    float4 b = x4[2 * t + 1];
    ushort8 o;
    o[0] = f2bf(a.x); o[1] = f2bf(a.y); o[2] = f2bf(a.z); o[3] = f2bf(a.w);
    o[4] = f2bf(b.x); o[5] = f2bf(b.y); o[6] = f2bf(b.z); o[7] = f2bf(b.w);
    ((ushort8*)xb)[t] = o;
}

// Stage one K-half sub-tile (256 rows x 32 cols bf16 = 16 KB, contiguous LDS,
// linear layout): 2 global_load_lds x 512 threads x 16B.
#define STAGE_SUB(gbase, lds_sub, kcol0)                                      \
  do {                                                                        \
    _Pragma("unroll")                                                         \
    for (int _g = 0; _g < 2; ++_g) {                                          \
      const int _i = _g * 512 + tid;       /* 0..1023 */                      \
      const int _r = _i >> 2;              /* row 0..255 */                   \
      const int _c = (_i & 3) << 3;        /* col elem 0,8,16,24 */           \
      __builtin_amdgcn_global_load_lds(                                       \
          (const __attribute__((address_space(1))) void*)((gbase) +           \
              (size_t)_r * K_DIM + (kcol0) + _c),                             \
          (__attribute__((address_space(3))) void*)((lds_sub) +               \
              (_g * 512 + wave * 64) * 8),                                    \
          16, 0, 0);                                                          \
    }                                                                         \
  } while (0)

// Frag reads from a [256][32] K-half into NAMED register sets (rule 20).
// 64B rows -> 2-way bank aliasing only (free per m136).
#define DS_A4(dst, sub, rbase)                                                \
  dst[0] = *(const short8*)((sub) + ((rbase) +  0 + lr) * 32 + q8);           \
  dst[1] = *(const short8*)((sub) + ((rbase) + 16 + lr) * 32 + q8);           \
  dst[2] = *(const short8*)((sub) + ((rbase) + 32 + lr) * 32 + q8);           \
  dst[3] = *(const short8*)((sub) + ((rbase) + 48 + lr) * 32 + q8);

#define DS_B4(dst, sub)                                                       \
  dst[0] = *(const short8*)((sub) + (wn * 64 +  0 + lr) * 32 + q8);           \
  dst[1] = *(const short8*)((sub) + (wn * 64 + 16 + lr) * 32 + q8);           \
  dst[2] = *(const short8*)((sub) + (wn * 64 + 32 + lr) * 32 + q8);           \
  dst[3] = *(const short8*)((sub) + (wn * 64 + 48 + lr) * 32 + q8);

#define MFMA16(MI0, Ar, Br)                                                   \
  do {                                                                        \
    _Pragma("unroll")                                                         \
    for (int _m = 0; _m < 4; ++_m) {                                          \
      _Pragma("unroll")                                                       \
      for (int _n = 0; _n < 4; ++_n)                                          \
        acc[(MI0) + _m][_n] = __builtin_amdgcn_mfma_f32_16x16x32_bf16(        \
            Ar[_m], Br[_n], acc[(MI0) + _m][_n], 0, 0, 0);                    \
    }                                                                         \
  } while (0)

#define BAR    asm volatile("s_barrier" ::: "memory")
#define VMCNT4 asm volatile("s_waitcnt vmcnt(4)" ::: "memory")
#define LGKM0  do { asm volatile("s_waitcnt lgkmcnt(0)" ::: "memory");        \
                    __builtin_amdgcn_sched_barrier(0); } while (0)

// Phase compute: barrier -> per-wave lgkm -> prioritized 16-MFMA -> barrier.
#define PH_MFMA(MI0, Ar, Br)                                                  \
  BAR; LGKM0;                                                                 \
  __builtin_amdgcn_s_setprio(1);                                              \
  MFMA16(MI0, Ar, Br);                                                        \
  __builtin_amdgcn_s_setprio(0);                                              \
  __builtin_amdgcn_sched_barrier(0);                                          \
  BAR;

// 256x256 tile, BK=64, 8 waves (2M x 4N), dbuf-2 K-half LDS, 4-phase lockstep
// with COUNTED vmcnt(4) twice per tile (never 0 in loop), 1 half staged/phase
// at distance 1.5-2 tiles. Ledger invariant: 8 outstanding before each vmcnt.
__global__ __launch_bounds__(512, 2) void gemm256(const unsigned short* __restrict__ A,
                                                  const unsigned short* __restrict__ B,
                                                  const float* __restrict__ bias,
                                                  float* __restrict__ C) {
    __shared__ unsigned short As[2][2][BM * 32];   // [buf][khalf], 64 KB
    __shared__ unsigned short Bs[2][2][BN * 32];   // 64 KB -> 128 KB total

    const int tid  = threadIdx.x;
    const int wave = tid >> 6;
    const int lane = tid & 63;
    const int wm = wave >> 2;               // 0..1 -> A 128-row slab
    const int wn = wave & 3;                // 0..3 -> B 64-row slab
    const int lr = lane & 15;
    const int q8 = (lane >> 4) << 3;        // k elem offset within 32-col half

    // XCD-aware bijective swizzle: grid = 1376, 1376 % 8 == 0.
    const int nbn = N_DIM / BN;             // 43
    const int cpx = (int)gridDim.x >> 3;    // 172
    const int bid = (int)blockIdx.x;
    const int swz = (bid & 7) * cpx + (bid >> 3);
    const int bm = swz / nbn;
    const int bn = swz % nbn;

    const unsigned short* Ab = A + (size_t)bm * BM * K_DIM;
    const unsigned short* Bb = B + (size_t)bn * BN * K_DIM;

    f32x4 acc[8][4];
#pragma unroll
    for (int i = 0; i < 8; ++i)
#pragma unroll
        for (int j = 0; j < 4; ++j)
#pragma unroll
            for (int v = 0; v < 4; ++v) acc[i][j][v] = 0.0f;

    // Prologue: A0(0),B0(0),A1(0),B1(0),A0(1),B0(1) = 12 loads;
    // vmcnt(4) retires tile 0's 8, leaves {A0(1),B0(1)} = steady-state entry.
    STAGE_SUB(Ab, &As[0][0][0], 0);
    STAGE_SUB(Bb, &Bs[0][0][0], 0);
    STAGE_SUB(Ab, &As[0][1][0], 32);
    STAGE_SUB(Bb, &Bs[0][1][0], 32);
    STAGE_SUB(Ab, &As[1][0][0], BK);
    STAGE_SUB(Bb, &Bs[1][0][0], BK);
    VMCNT4;
    BAR;

    short8 aA[4], aB[4], aC[4], aD[4], bE[4], bO[4];

#pragma unroll 1
    for (int t = 0; t < TILES; ++t) {
        const int p = t & 1;
        int t1 = t + 1; if (t1 >= TILES) t1 -= TILES;  // tail wrap: harmless
        int t2 = t + 2; if (t2 >= TILES) t2 -= TILES;  // garbage into dead halves
        const int k1 = t1 * BK;
        const int k2 = t2 * BK;

        // ---- P1: mi 0..3 kk=0; stage A-kh1(t+1) -> [p^1][1]
        //      (last read P4(t-1), >=1 barrier ago) ----
        DS_A4(aA, &As[p][0][0], wm * 128);
        DS_B4(bE, &Bs[p][0][0]);
        STAGE_SUB(Ab, &As[p ^ 1][1][0], k1 + 32);
        PH_MFMA(0, aA, bE);

        // ---- P2: mi 4..7 kk=0 (bE reused); stage B-kh1(t+1) -> [p^1][1];
        //      COUNTED vmcnt: 8 outstanding -> 4, retires A0(t+1),B0(t+1)
        //      (first read at P1(t+1), >=3 barriers later) ----
        DS_A4(aB, &As[p][0][0], wm * 128 + 64);
        STAGE_SUB(Bb, &Bs[p ^ 1][1][0], k1 + 32);
        VMCNT4;
        PH_MFMA(4, aB, bE);

        // ---- P3: mi 0..3 kk=32; stage A-kh0(t+2) -> [p][0]
        //      (its last readers were P1/P2 of THIS tile, 2 barriers ago) ----
        DS_A4(aC, &As[p][1][0], wm * 128);
        DS_B4(bO, &Bs[p][1][0]);
        STAGE_SUB(Ab, &As[p][0][0], k2);
        PH_MFMA(0, aC, bO);

        // ---- P4: mi 4..7 kk=32 (bO reused); stage B-kh0(t+2) -> [p][0];
        //      COUNTED vmcnt: retires A1(t+1),B1(t+1) (read at P3(t+1)) ----
        DS_A4(aD, &As[p][1][0], wm * 128 + 64);
        STAGE_SUB(Bb, &Bs[p][0][0], k2);
        VMCNT4;
        PH_MFMA(4, aD, bO);
    }
    // Drain the 8 in-flight garbage loads before LDS dealloc / retire.
    asm volatile("s_waitcnt vmcnt(0)" ::: "memory");

    // Epilogue: C/D layout col = lane&15, row = (lane>>4)*4 + v (m89/m91).
    const int row0 = bm * BM + wm * 128 + ((lane >> 4) << 2);
    const int col0 = bn * BN + wn * 64 + lr;
#pragma unroll
    for (int ni = 0; ni < 4; ++ni) {
        const int col = col0 + ni * 16;
        const float bv = bias[col];
#pragma unroll
        for (int mi = 0; mi < 8; ++mi) {
#pragma unroll
            for (int v = 0; v < 4; ++v) {
                C[(size_t)(row0 + mi * 16 + v) * N_DIM + col] = acc[mi][ni][v] + bv;
            }
        }
    }
}

extern "C" void kernel_launch(void* const* d_in, const int* in_sizes, int n_in,
                              void* d_out, int out_size, void* d_ws, size_t ws_size,
                              hipStream_t stream) {
    const float* x    = (const float*)d_in[0];   // [4,2048,4096] f32
    const int*   wq   = (const int*)d_in[1];     // [11008,4096] int32 in 0..15
    const float* am   = (const float*)d_in[2];   // [11008,64] f32
    const float* bias = (const float*)d_in[3];   // [11008] f32
    float* out = (float*)d_out;                  // [4,2048,11008] f32

    const size_t w_elems = (size_t)N_DIM * K_DIM;
    const size_t x_elems = (size_t)M_DIM * K_DIM;
    const size_t need = (w_elems + x_elems) * sizeof(unsigned short);
    if (ws_size < need) return;

    unsigned short* wbf = (unsigned short*)d_ws;
    unsigned short* xbf = wbf + w_elems;

    nf4_dequant_w<<<(int)(w_elems / 8 / 256), 256, 0, stream>>>(wq, am, wbf);
    x_to_bf16<<<(int)(x_elems / 8 / 256), 256, 0, stream>>>(x, xbf);

    const int grid = (M_DIM / BM) * (N_DIM / BN);   // 32 * 43 = 1376
    gemm256<<<grid, 512, 0, stream>>>(xbf, wbf, bias, out);
}